// Round 1
// baseline (152.838 us; speedup 1.0000x reference)
//
#include <hip/hip_runtime.h>
#include <hip/hip_bf16.h>

// ---- problem constants ----
#define T_DIM   2048
#define A_DIM   64
#define N_TOK   (T_DIM * A_DIM)     // 131072
#define RAWOB   120
#define N_TP    5
#define E_EXP   10
#define D_DIM   126                  // RAWOB + N_TP + 1
#define DP      128                  // padded K (row 126 = bias, row 127 = 0)
#define H_DIM   128
#define N_ACT   16
#define CAP     14336                // per-expert capacity (mean 13107, +11 sigma)
#define BTOK    256                  // tokens per block (8 waves x 32)
#define MAXC    (CAP / BTOK)         // 56 chunks per expert
#define LOGITS_SZ (N_TOK * N_ACT)    // 2097152

typedef __bf16 bh8 __attribute__((ext_vector_type(8)));
typedef ushort u16x8 __attribute__((ext_vector_type(8)));
typedef ushort u16x4 __attribute__((ext_vector_type(4)));
typedef short  s16x4 __attribute__((ext_vector_type(4)));
typedef float  f32x4 __attribute__((ext_vector_type(4)));

__device__ __forceinline__ f32x4 mfma16(bh8 a, bh8 b, f32x4 c) {
    return __builtin_amdgcn_mfma_f32_16x16x32_bf16(a, b, c, 0, 0, 0);
}
// K=16 variant: per-lane k-quads (k = 4*lq + j) — matches swapped-L1 output layout
__device__ __forceinline__ f32x4 mfma16k16(s16x4 a, s16x4 b, f32x4 c) {
    return __builtin_amdgcn_mfma_f32_16x16x16bf16_1k(a, b, c, 0, 0, 0);
}

__device__ __forceinline__ ushort f2bf(float f) {
    unsigned x = __builtin_bit_cast(unsigned, f);
    unsigned r = (x + 0x7fffu + ((x >> 16) & 1u)) >> 16;   // round-nearest-even
    return (ushort)r;
}

#define W1P_N (E_EXP * H_DIM * DP)           // 163840 ushorts
#define W2P_N (E_EXP * N_ACT * H_DIM)        // 20480
#define WC1P_N (DP * DP)                     // 16384

// ---------------- kernel 0: merged prep (fragment packing) + bucket ----------------
// blocks 0..43:   W1/Wc1 packing (bias folded into padded row 126)
// blocks 44..123: W2 packing (16x16x16 B-frag layout)
// blocks 124..251: token bucketing (counts pre-zeroed via hipMemsetAsync)
#define PB_BLOCKS 252

__global__ __launch_bounds__(256) void prep_bucket_kernel(
    const float* __restrict__ W1, const float* __restrict__ W2,
    const float* __restrict__ Wc1, const float* __restrict__ b1,
    const float* __restrict__ bc1, const int* __restrict__ pick,
    int* __restrict__ counts, int* __restrict__ order,
    ushort* __restrict__ W1p, ushort* __restrict__ W2p, ushort* __restrict__ Wc1p)
{
    int bx = blockIdx.x, tid = threadIdx.x;
    if (bx < 44) {
        __shared__ ushort st[32][130];   // 32 d-rows x 128 n, padded
        const float* src;
        const float* bias;
        ushort* dstbase;
        int kt;
        if (bx < 40) {                   // W1: e = bx>>2, kt = bx&3
            int e = bx >> 2;
            kt = bx & 3;
            src = W1 + (e * D_DIM + kt * 32) * H_DIM;
            bias = b1 + e * H_DIM;
            dstbase = W1p + e * (H_DIM * DP);
        } else {                         // Wc1: kt = bx-40
            kt = bx - 40;
            src = Wc1 + kt * 32 * H_DIM;
            bias = bc1;
            dstbase = Wc1p;
        }
        int dmax = D_DIM - kt * 32;      // 32,32,32,30
#pragma unroll
        for (int p = 0; p < 16; ++p) {
            int idx = p * 256 + tid;
            int dd = idx >> 7, n = idx & 127;
            float v;
            if (dd < dmax)                    v = src[dd * H_DIM + n];   // coalesced in n
            else if (kt == 3 && dd == 30)     v = bias[n];               // bias row (k=126)
            else                              v = 0.f;                   // k=127 pad
            st[dd][n] = f2bf(v);
        }
        __syncthreads();
#pragma unroll
        for (int p = 0; p < 16; ++p) {
            int idx = p * 256 + tid;
            int dd = idx >> 7, n = idx & 127;
            // frag position: nt=n>>4, lm=n&15, lq=dd>>3, j=dd&7
            dstbase[((n >> 4) * 4 + kt) * 512 + ((dd >> 3) * 16 + (n & 15)) * 8 + (dd & 7)]
                = st[dd][n];
        }
    } else if (bx < 124) {
        // W2 packed as 16x16x16 B-frags: tile kk (k = kk*16 + 4*lq + j), col = lm
        int i = (bx - 44) * 256 + tid;   // [0, 20480)
        int e   = i >> 11;
        int rem = i & 2047;
        int kk  = rem >> 8;
        int idx = rem & 255;
        int l = idx >> 2, j = idx & 3;
        int lq = l >> 4, lm = l & 15;
        W2p[i] = f2bf(W2[(e * H_DIM + kk * 16 + lq * 4 + j) * N_ACT + lm]);
    } else {
        // ---- bucket: counts padded, expert e at counts[e*16] ----
        __shared__ int lc[E_EXP], lb[E_EXP], lcur[E_EXP];
        if (tid < E_EXP) { lc[tid] = 0; lcur[tid] = 0; }
        __syncthreads();
        int base = (bx - 124) * 1024;
        int e4[4];
#pragma unroll
        for (int it = 0; it < 4; ++it) {
            e4[it] = pick[base + it * 256 + tid];
            atomicAdd(&lc[e4[it]], 1);
        }
        __syncthreads();
        if (tid < E_EXP) lb[tid] = atomicAdd(&counts[tid * 16], lc[tid]);
        __syncthreads();
#pragma unroll
        for (int it = 0; it < 4; ++it) {
            int e = e4[it];
            int pos = lb[e] + atomicAdd(&lcur[e], 1);
            if (pos < CAP) order[e * CAP + pos] = base + it * 256 + tid;
        }
    }
}

// ---------------- kernel 1: LDS-staged-weights fused expert + critic ------------
// 512 threads = 8 waves x 32 tokens. LDS = 36 KB (weights only; hbuf eliminated
// via swapped-operand L1 -> register h -> 16x16x16 L2). 4 blocks/CU, 32 waves/CU.
__global__ __launch_bounds__(512, 8) void moe_kernel(
    const float* __restrict__ obs, const int* __restrict__ hete_type,
    const int* __restrict__ gp_sel,
    const float* __restrict__ b2, const float* __restrict__ bc2,
    const int* __restrict__ counts, const int* __restrict__ order,
    const ushort* __restrict__ W1p, const ushort* __restrict__ W2p,
    const ushort* __restrict__ Wc1p, const float* __restrict__ Wc2,
    float* __restrict__ out)
{
    __shared__ __align__(16) ushort wlds[18432];   // 32KB W1e/Wc1 + 4KB W2e

    const int bx = blockIdx.x;
    const int e = bx % E_EXP;
    const int c = bx / E_EXP;
    const int cnt = counts[e * 16];
    const int start = c * BTOK;
    if (start >= cnt) return;                   // uniform block exit (before barriers)

    const int tid = threadIdx.x;
    const int w = tid >> 6;
    const int base = start + w * 32;            // this wave's token offset (may exceed cnt)
    const int l = tid & 63;
    const int lm = l & 15;
    const int lq = l >> 4;

    // ---- stage W1e (32KB) + W2e (4KB) packed frags into LDS (512 threads) ----
    {
        const u16x8* s1 = (const u16x8*)(const void*)(W1p + e * (H_DIM * DP));
        u16x8* d1 = (u16x8*)(void*)wlds;
#pragma unroll
        for (int p = 0; p < 4; ++p) d1[p * 512 + tid] = s1[p * 512 + tid];
        if (tid < 256)
            ((u16x8*)(void*)(wlds + 16384))[tid] =
                ((const u16x8*)(const void*)(W2p + e * 2048))[tid];
    }

    const int* ord_e = order + e * CAP;

    // ---- build A-fragments for 2 m-tiles directly from obs (+augment) ----
    // lane l holds x[token = base+mt*16+lm][k = kt*32 + lq*8 + j]; k=126 slot = 1.0
    bh8 a[2][4];
    int tokm[2];
#pragma unroll
    for (int mt = 0; mt < 2; ++mt) {
        const int slot = min(base + mt * 16 + lm, cnt - 1);
        const int tok = ord_e[slot];
        tokm[mt] = tok;
        const float* orow = obs + tok * RAWOB;
#pragma unroll
        for (int kt = 0; kt < 3; ++kt) {
            const float* p = orow + kt * 32 + lq * 8;
            float4 u0 = *(const float4*)(const void*)p;
            float4 u1 = *(const float4*)(const void*)(p + 4);
            u16x8 t;
            t[0] = f2bf(u0.x); t[1] = f2bf(u0.y); t[2] = f2bf(u0.z); t[3] = f2bf(u0.w);
            t[4] = f2bf(u1.x); t[5] = f2bf(u1.y); t[6] = f2bf(u1.z); t[7] = f2bf(u1.w);
            a[mt][kt] = __builtin_bit_cast(bh8, t);
        }
        u16x8 t;
        if (lq < 3) {   // k = 96..119 from obs
            const float* p = orow + 96 + lq * 8;
            float4 u0 = *(const float4*)(const void*)p;
            float4 u1 = *(const float4*)(const void*)(p + 4);
            t[0] = f2bf(u0.x); t[1] = f2bf(u0.y); t[2] = f2bf(u0.z); t[3] = f2bf(u0.w);
            t[4] = f2bf(u1.x); t[5] = f2bf(u1.y); t[6] = f2bf(u1.z); t[7] = f2bf(u1.w);
        } else {        // k = 120..127: [hete_type, gp_obs(5), 1.0 (bias), 0]
            int ht = hete_type[tok];
            int tt = tok >> 6;                  // token / A_DIM
            t[0] = f2bf((float)ht);
#pragma unroll
            for (int q = 0; q < N_TP; ++q) {
                float g = (q == ht) ? -1.0f : (float)gp_sel[tt * N_TP + q];
                t[1 + q] = f2bf(g);
            }
            t[6] = (ushort)0x3F80;              // 1.0 -> picks up bias row 126
            t[7] = 0;
        }
        a[mt][3] = __builtin_bit_cast(bh8, t);
    }

    const float bb  = b2[e * N_ACT + lm];
    const float bcv = bc2[0];

    __syncthreads();   // W1e/W2e staged

    // ---- expert path: swapped L1 (h^T in regs) -> ReLU/pack -> 16x16x16 L2 ----
    // L1: D = W1^T x^T : lane holds h[token=lm][n = nt*16 + lq*4 + r]
    // L2: y = h W2 via K=16 MFMA (k-quads 4*lq+j match L1 output directly)
#pragma unroll
    for (int mt = 0; mt < 2; ++mt) {
        f32x4 y = (f32x4){0.f, 0.f, 0.f, 0.f};
#pragma unroll
        for (int nt = 0; nt < 8; ++nt) {
            f32x4 ae = (f32x4){0.f, 0.f, 0.f, 0.f};
#pragma unroll
            for (int kt = 0; kt < 4; ++kt) {
                bh8 wf = *(const bh8*)(const void*)(wlds + (nt * 4 + kt) * 512 + l * 8);
                ae = mfma16(wf, a[mt][kt], ae);         // swapped operands
            }
            u16x4 hp;
            hp[0] = f2bf(fmaxf(ae[0], 0.f));
            hp[1] = f2bf(fmaxf(ae[1], 0.f));
            hp[2] = f2bf(fmaxf(ae[2], 0.f));
            hp[3] = f2bf(fmaxf(ae[3], 0.f));
            s16x4 w2f = *(const s16x4*)(const void*)(wlds + 16384 + nt * 256 + l * 4);
            y = mfma16k16(__builtin_bit_cast(s16x4, hp), w2f, y);
        }
#pragma unroll
        for (int r = 0; r < 4; ++r) {
            int m = mt * 16 + lq * 4 + r;
            if (base + m < cnt)
                out[ord_e[base + m] * N_ACT + lm] = y[r] + bb;
        }
    }

    __syncthreads();   // everyone done with W1e/W2e buffers

    // ---- re-stage Wc1p into the same buffer ----
    {
        const u16x8* s1 = (const u16x8*)(const void*)Wc1p;
        u16x8* d1 = (u16x8*)(void*)wlds;
#pragma unroll
        for (int p = 0; p < 4; ++p) d1[p * 512 + tid] = s1[p * 512 + tid];
    }
    __syncthreads();

    // ---- critic: swapped L1, per-lane dot with Wc2, 2-step lq reduction ----
    {
        float p0 = 0.f, p1 = 0.f;
#pragma unroll
        for (int nt = 0; nt < 8; ++nt) {
            f32x4 c0 = (f32x4){0.f,0.f,0.f,0.f}, c1 = c0;
#pragma unroll
            for (int kt = 0; kt < 4; ++kt) {
                bh8 wf = *(const bh8*)(const void*)(wlds + (nt * 4 + kt) * 512 + l * 8);
                c0 = mfma16(wf, a[0][kt], c0);
                c1 = mfma16(wf, a[1][kt], c1);
            }
            const float4 wc = *(const float4*)(const void*)(Wc2 + nt * 16 + lq * 4);
            p0 += fmaxf(c0[0], 0.f) * wc.x + fmaxf(c0[1], 0.f) * wc.y
                + fmaxf(c0[2], 0.f) * wc.z + fmaxf(c0[3], 0.f) * wc.w;
            p1 += fmaxf(c1[0], 0.f) * wc.x + fmaxf(c1[1], 0.f) * wc.y
                + fmaxf(c1[2], 0.f) * wc.z + fmaxf(c1[3], 0.f) * wc.w;
        }
        // lane (lq,lm) holds token lm's partial over its n-subset; sum over lq
        p0 += __shfl_xor(p0, 16, 64); p0 += __shfl_xor(p0, 32, 64);
        p1 += __shfl_xor(p1, 16, 64); p1 += __shfl_xor(p1, 32, 64);
        if (lq == 0) {
            if (base + lm < cnt)      out[LOGITS_SZ + tokm[0]] = p0 + bcv;
            if (base + 16 + lm < cnt) out[LOGITS_SZ + tokm[1]] = p1 + bcv;
        }
    }
}

extern "C" void kernel_launch(void* const* d_in, const int* in_sizes, int n_in,
                              void* d_out, int out_size, void* d_ws, size_t ws_size,
                              hipStream_t stream) {
    const float* obs  = (const float*)d_in[0];
    const int*   pick = (const int*)d_in[1];
    const int*   htyp = (const int*)d_in[2];
    const int*   gp   = (const int*)d_in[3];
    const float* W1   = (const float*)d_in[4];
    const float* b1   = (const float*)d_in[5];
    const float* W2   = (const float*)d_in[6];
    const float* b2   = (const float*)d_in[7];
    const float* Wc1  = (const float*)d_in[8];
    const float* bc1  = (const float*)d_in[9];
    const float* Wc2  = (const float*)d_in[10];
    const float* bc2  = (const float*)d_in[11];
    float* out = (float*)d_out;

    int*    counts = (int*)d_ws;              // 160 ints (padded, e -> counts[e*16])
    int*    order  = counts + 160;            // E_EXP * CAP ints
    ushort* W1p    = (ushort*)(order + E_EXP * CAP);
    ushort* W2p    = W1p + W1P_N;
    ushort* Wc1p   = W2p + W2P_N;

    hipMemsetAsync(counts, 0, 160 * sizeof(int), stream);
    prep_bucket_kernel<<<PB_BLOCKS, 256, 0, stream>>>(
        W1, W2, Wc1, b1, bc1, pick, counts, order, W1p, W2p, Wc1p);
    moe_kernel<<<E_EXP * MAXC, 512, 0, stream>>>(
        obs, htyp, gp, b2, bc2, counts, order,
        W1p, W2p, Wc1p, Wc2, out);
}

// Round 2
// 132.958 us; speedup vs baseline: 1.1495x; 1.1495x over previous
//
#include <hip/hip_runtime.h>
#include <hip/hip_bf16.h>

// ---- problem constants ----
#define T_DIM   2048
#define A_DIM   64
#define N_TOK   (T_DIM * A_DIM)     // 131072
#define RAWOB   120
#define N_TP    5
#define E_EXP   10
#define D_DIM   126                  // RAWOB + N_TP + 1
#define DP      128                  // padded K (row 126 = bias, row 127 = 0)
#define H_DIM   128
#define N_ACT   16
#define CAP     14336                // per-expert capacity (mean 13107, +11 sigma)
#define BTOK    128                  // tokens per block (8 waves x 16)
#define MAXC    (CAP / BTOK)         // 112 chunks per expert
#define LOGITS_SZ (N_TOK * N_ACT)    // 2097152

typedef __bf16 bh8 __attribute__((ext_vector_type(8)));
typedef ushort u16x8 __attribute__((ext_vector_type(8)));
typedef ushort u16x4 __attribute__((ext_vector_type(4)));
typedef short  s16x4 __attribute__((ext_vector_type(4)));
typedef float  f32x4 __attribute__((ext_vector_type(4)));

__device__ __forceinline__ f32x4 mfma16(bh8 a, bh8 b, f32x4 c) {
    return __builtin_amdgcn_mfma_f32_16x16x32_bf16(a, b, c, 0, 0, 0);
}
// K=16 variant: per-lane k-quads (k = 4*lq + j) — matches swapped-L1 output layout
__device__ __forceinline__ f32x4 mfma16k16(s16x4 a, s16x4 b, f32x4 c) {
    return __builtin_amdgcn_mfma_f32_16x16x16bf16_1k(a, b, c, 0, 0, 0);
}

__device__ __forceinline__ ushort f2bf(float f) {
    unsigned x = __builtin_bit_cast(unsigned, f);
    unsigned r = (x + 0x7fffu + ((x >> 16) & 1u)) >> 16;   // round-nearest-even
    return (ushort)r;
}

#define W1P_N (E_EXP * H_DIM * DP)           // 163840 ushorts
#define W2P_N (E_EXP * N_ACT * H_DIM)        // 20480
#define WC1P_N (DP * DP)                     // 16384

// ---------------- kernel 0: merged prep (fragment packing) + bucket ----------------
// blocks 0..43:   W1/Wc1 packing (bias folded into padded row 126)
// blocks 44..123: W2 packing (16x16x16 B-frag layout)
// blocks 124..251: token bucketing (counts pre-zeroed via hipMemsetAsync)
#define PB_BLOCKS 252

__global__ __launch_bounds__(256) void prep_bucket_kernel(
    const float* __restrict__ W1, const float* __restrict__ W2,
    const float* __restrict__ Wc1, const float* __restrict__ b1,
    const float* __restrict__ bc1, const int* __restrict__ pick,
    int* __restrict__ counts, int* __restrict__ order,
    ushort* __restrict__ W1p, ushort* __restrict__ W2p, ushort* __restrict__ Wc1p)
{
    int bx = blockIdx.x, tid = threadIdx.x;
    if (bx < 44) {
        __shared__ ushort st[32][130];   // 32 d-rows x 128 n, padded
        const float* src;
        const float* bias;
        ushort* dstbase;
        int kt;
        if (bx < 40) {                   // W1: e = bx>>2, kt = bx&3
            int e = bx >> 2;
            kt = bx & 3;
            src = W1 + (e * D_DIM + kt * 32) * H_DIM;
            bias = b1 + e * H_DIM;
            dstbase = W1p + e * (H_DIM * DP);
        } else {                         // Wc1: kt = bx-40
            kt = bx - 40;
            src = Wc1 + kt * 32 * H_DIM;
            bias = bc1;
            dstbase = Wc1p;
        }
        int dmax = D_DIM - kt * 32;      // 32,32,32,30
#pragma unroll
        for (int p = 0; p < 16; ++p) {
            int idx = p * 256 + tid;
            int dd = idx >> 7, n = idx & 127;
            float v;
            if (dd < dmax)                    v = src[dd * H_DIM + n];   // coalesced in n
            else if (kt == 3 && dd == 30)     v = bias[n];               // bias row (k=126)
            else                              v = 0.f;                   // k=127 pad
            st[dd][n] = f2bf(v);
        }
        __syncthreads();
#pragma unroll
        for (int p = 0; p < 16; ++p) {
            int idx = p * 256 + tid;
            int dd = idx >> 7, n = idx & 127;
            // frag position: nt=n>>4, lm=n&15, lq=dd>>3, j=dd&7
            dstbase[((n >> 4) * 4 + kt) * 512 + ((dd >> 3) * 16 + (n & 15)) * 8 + (dd & 7)]
                = st[dd][n];
        }
    } else if (bx < 124) {
        // W2 packed as 16x16x16 B-frags: tile kk (k = kk*16 + 4*lq + j), col = lm
        int i = (bx - 44) * 256 + tid;   // [0, 20480)
        int e   = i >> 11;
        int rem = i & 2047;
        int kk  = rem >> 8;
        int idx = rem & 255;
        int l = idx >> 2, j = idx & 3;
        int lq = l >> 4, lm = l & 15;
        W2p[i] = f2bf(W2[(e * H_DIM + kk * 16 + lq * 4 + j) * N_ACT + lm]);
    } else {
        // ---- bucket: counts padded, expert e at counts[e*16] ----
        __shared__ int lc[E_EXP], lb[E_EXP], lcur[E_EXP];
        if (tid < E_EXP) { lc[tid] = 0; lcur[tid] = 0; }
        __syncthreads();
        int base = (bx - 124) * 1024;
        int e4[4];
#pragma unroll
        for (int it = 0; it < 4; ++it) {
            e4[it] = pick[base + it * 256 + tid];
            atomicAdd(&lc[e4[it]], 1);
        }
        __syncthreads();
        if (tid < E_EXP) lb[tid] = atomicAdd(&counts[tid * 16], lc[tid]);
        __syncthreads();
#pragma unroll
        for (int it = 0; it < 4; ++it) {
            int e = e4[it];
            int pos = lb[e] + atomicAdd(&lcur[e], 1);
            if (pos < CAP) order[e * CAP + pos] = base + it * 256 + tid;
        }
    }
}

// ---------------- kernel 1: LDS-staged-weights fused expert + critic ------------
// 512 threads = 8 waves x 16 tokens (1 m-frag per wave -> a[4] = 16 VGPRs, no
// spill inside the 64-VGPR budget of 8 waves/SIMD). LDS = 36 KB -> 4 blocks/CU,
// 32 waves/CU; ~1030 active blocks fit the chip's 1024 block slots in one round.
__global__ __launch_bounds__(512, 8) void moe_kernel(
    const float* __restrict__ obs, const int* __restrict__ hete_type,
    const int* __restrict__ gp_sel,
    const float* __restrict__ b2, const float* __restrict__ bc2,
    const int* __restrict__ counts, const int* __restrict__ order,
    const ushort* __restrict__ W1p, const ushort* __restrict__ W2p,
    const ushort* __restrict__ Wc1p, const float* __restrict__ Wc2,
    float* __restrict__ out)
{
    __shared__ __align__(16) ushort wlds[18432];   // 32KB W1e/Wc1 + 4KB W2e

    const int bx = blockIdx.x;
    const int e = bx % E_EXP;
    const int c = bx / E_EXP;
    const int cnt = counts[e * 16];
    const int start = c * BTOK;
    if (start >= cnt) return;                   // uniform block exit (before barriers)

    const int tid = threadIdx.x;
    const int w = tid >> 6;
    const int base = start + w * 16;            // this wave's token offset (may exceed cnt)
    const int l = tid & 63;
    const int lm = l & 15;
    const int lq = l >> 4;

    // ---- stage W1e (32KB) + W2e (4KB) packed frags into LDS (512 threads) ----
    {
        const u16x8* s1 = (const u16x8*)(const void*)(W1p + e * (H_DIM * DP));
        u16x8* d1 = (u16x8*)(void*)wlds;
#pragma unroll
        for (int p = 0; p < 4; ++p) d1[p * 512 + tid] = s1[p * 512 + tid];
        if (tid < 256)
            ((u16x8*)(void*)(wlds + 16384))[tid] =
                ((const u16x8*)(const void*)(W2p + e * 2048))[tid];
    }

    const int* ord_e = order + e * CAP;

    // ---- build A-fragment for this wave's 16 tokens directly from obs ----
    // lane l holds x[token = base+lm][k = kt*32 + lq*8 + j]; k=126 slot = 1.0 (bias)
    bh8 a[4];
    const int slot = min(base + lm, cnt - 1);
    const int tok = ord_e[slot];
    {
        const float* orow = obs + tok * RAWOB;
#pragma unroll
        for (int kt = 0; kt < 3; ++kt) {
            const float* p = orow + kt * 32 + lq * 8;
            float4 u0 = *(const float4*)(const void*)p;
            float4 u1 = *(const float4*)(const void*)(p + 4);
            u16x8 t;
            t[0] = f2bf(u0.x); t[1] = f2bf(u0.y); t[2] = f2bf(u0.z); t[3] = f2bf(u0.w);
            t[4] = f2bf(u1.x); t[5] = f2bf(u1.y); t[6] = f2bf(u1.z); t[7] = f2bf(u1.w);
            a[kt] = __builtin_bit_cast(bh8, t);
        }
        u16x8 t;
        if (lq < 3) {   // k = 96..119 from obs
            const float* p = orow + 96 + lq * 8;
            float4 u0 = *(const float4*)(const void*)p;
            float4 u1 = *(const float4*)(const void*)(p + 4);
            t[0] = f2bf(u0.x); t[1] = f2bf(u0.y); t[2] = f2bf(u0.z); t[3] = f2bf(u0.w);
            t[4] = f2bf(u1.x); t[5] = f2bf(u1.y); t[6] = f2bf(u1.z); t[7] = f2bf(u1.w);
        } else {        // k = 120..127: [hete_type, gp_obs(5), 1.0 (bias), 0]
            int ht = hete_type[tok];
            int tt = tok >> 6;                  // token / A_DIM
            t[0] = f2bf((float)ht);
#pragma unroll
            for (int q = 0; q < N_TP; ++q) {
                float g = (q == ht) ? -1.0f : (float)gp_sel[tt * N_TP + q];
                t[1 + q] = f2bf(g);
            }
            t[6] = (ushort)0x3F80;              // 1.0 -> picks up bias row 126
            t[7] = 0;
        }
        a[3] = __builtin_bit_cast(bh8, t);
    }

    const float bb  = b2[e * N_ACT + lm];
    const float bcv = bc2[0];

    __syncthreads();   // W1e/W2e staged

    // ---- expert path: swapped L1 (h^T in regs) -> ReLU/pack -> 16x16x16 L2 ----
    // L1: D = W1^T x^T : lane holds h[token=lm][n = nt*16 + lq*4 + r]
    // L2: y = h W2 via K=16 MFMA (k-quads 4*lq+j match L1 output directly)
    {
        f32x4 y = (f32x4){0.f, 0.f, 0.f, 0.f};
#pragma unroll
        for (int nt = 0; nt < 8; ++nt) {
            f32x4 ae = (f32x4){0.f, 0.f, 0.f, 0.f};
#pragma unroll
            for (int kt = 0; kt < 4; ++kt) {
                bh8 wf = *(const bh8*)(const void*)(wlds + (nt * 4 + kt) * 512 + l * 8);
                ae = mfma16(wf, a[kt], ae);             // swapped operands
            }
            u16x4 hp;
            hp[0] = f2bf(fmaxf(ae[0], 0.f));
            hp[1] = f2bf(fmaxf(ae[1], 0.f));
            hp[2] = f2bf(fmaxf(ae[2], 0.f));
            hp[3] = f2bf(fmaxf(ae[3], 0.f));
            s16x4 w2f = *(const s16x4*)(const void*)(wlds + 16384 + nt * 256 + l * 4);
            y = mfma16k16(__builtin_bit_cast(s16x4, hp), w2f, y);
        }
#pragma unroll
        for (int r = 0; r < 4; ++r) {
            int m = lq * 4 + r;
            if (base + m < cnt)
                out[ord_e[base + m] * N_ACT + lm] = y[r] + bb;
        }
    }

    __syncthreads();   // everyone done with W1e/W2e buffers

    // ---- re-stage Wc1p into the same buffer ----
    {
        const u16x8* s1 = (const u16x8*)(const void*)Wc1p;
        u16x8* d1 = (u16x8*)(void*)wlds;
#pragma unroll
        for (int p = 0; p < 4; ++p) d1[p * 512 + tid] = s1[p * 512 + tid];
    }
    __syncthreads();

    // ---- critic: swapped L1, per-lane dot with Wc2, 2-step lq reduction ----
    {
        float p0 = 0.f;
#pragma unroll
        for (int nt = 0; nt < 8; ++nt) {
            f32x4 c0 = (f32x4){0.f,0.f,0.f,0.f};
#pragma unroll
            for (int kt = 0; kt < 4; ++kt) {
                bh8 wf = *(const bh8*)(const void*)(wlds + (nt * 4 + kt) * 512 + l * 8);
                c0 = mfma16(wf, a[kt], c0);
            }
            const float4 wc = *(const float4*)(const void*)(Wc2 + nt * 16 + lq * 4);
            p0 += fmaxf(c0[0], 0.f) * wc.x + fmaxf(c0[1], 0.f) * wc.y
                + fmaxf(c0[2], 0.f) * wc.z + fmaxf(c0[3], 0.f) * wc.w;
        }
        // lane (lq,lm) holds token lm's partial over its n-subset; sum over lq
        p0 += __shfl_xor(p0, 16, 64);
        p0 += __shfl_xor(p0, 32, 64);
        if (lq == 0 && base + lm < cnt)
            out[LOGITS_SZ + tok] = p0 + bcv;
    }
}

extern "C" void kernel_launch(void* const* d_in, const int* in_sizes, int n_in,
                              void* d_out, int out_size, void* d_ws, size_t ws_size,
                              hipStream_t stream) {
    const float* obs  = (const float*)d_in[0];
    const int*   pick = (const int*)d_in[1];
    const int*   htyp = (const int*)d_in[2];
    const int*   gp   = (const int*)d_in[3];
    const float* W1   = (const float*)d_in[4];
    const float* b1   = (const float*)d_in[5];
    const float* W2   = (const float*)d_in[6];
    const float* b2   = (const float*)d_in[7];
    const float* Wc1  = (const float*)d_in[8];
    const float* bc1  = (const float*)d_in[9];
    const float* Wc2  = (const float*)d_in[10];
    const float* bc2  = (const float*)d_in[11];
    float* out = (float*)d_out;

    int*    counts = (int*)d_ws;              // 160 ints (padded, e -> counts[e*16])
    int*    order  = counts + 160;            // E_EXP * CAP ints
    ushort* W1p    = (ushort*)(order + E_EXP * CAP);
    ushort* W2p    = W1p + W1P_N;
    ushort* Wc1p   = W2p + W2P_N;

    hipMemsetAsync(counts, 0, 160 * sizeof(int), stream);
    prep_bucket_kernel<<<PB_BLOCKS, 256, 0, stream>>>(
        W1, W2, Wc1, b1, bc1, pick, counts, order, W1p, W2p, Wc1p);
    moe_kernel<<<E_EXP * MAXC, 512, 0, stream>>>(
        obs, htyp, gp, b2, bc2, counts, order,
        W1p, W2p, Wc1p, Wc2, out);
}